// Round 12
// baseline (228.554 us; speedup 1.0000x reference)
//
#include <hip/hip_runtime.h>

// Integrate-and-fire SNN forward (IF_88957362634870).
// x: 8 frames of N = 4,194,304 fp32; out: 8 frames.
//
// Policy matrix complete: NT/NT ~70us (R11), NT/plain ~72us (R13),
// cached/NT ~84us (R12). Fused kernel streams 268 MB at 3.8 TB/s mixed;
// fill does 6.6 TB/s write-only. Never measured: pure-read NT rate.
//
// R14: direction-pure split. sc = k*thre, k integer in [-7,15] -> the
// entire intermediate state is 1 B/elem = 4 MiB (fits L2/IF$ trivially).
// K1: NT-read x (134 MB) -> compute k -> plain-store char4 (4 MiB, stays
// in cache). K2: plain-load counts (IF$ hit) -> NT-store out (134 MB).
// out[t] = (k > t) ? thre : 0 -- integer form of the R7/R8-verified
// closed form (exact for thre = 0.125 > 8e-5).
// Predict: K1 FETCH~134MB/WRITE~4MB, K2 FETCH<10MB/WRITE~131MB.
// If pure reads ~6 TB/s: K1~25us + K2~22us -> dur ~205. If reads cap
// ~2.5 TB/s: K1~54us -> dur ~230 => reads are the machine cap, fused
// config was already the floor (conclude roofline).

#define T1 8
#define T2 8
#define L_DIV 8.0f
#define EPS_C (-8e-05f)
#define G 2            // float4-groups per thread

typedef float fvec4 __attribute__((ext_vector_type(4)));
typedef char  cvec4 __attribute__((ext_vector_type(4)));

// ---------------- K1: read-phase (NT loads, tiny cached count store) ----
__global__ __launch_bounds__(256) void if_count(
    const fvec4* __restrict__ x,
    const float* __restrict__ thresh,
    cvec4* __restrict__ cnt,
    int n4)
{
    const int base = blockIdx.x * (256 * G) + threadIdx.x;
    const float thre = thresh[0] / L_DIV;

    fvec4 xv[G][T1];
    #pragma unroll
    for (int t = 0; t < T1; ++t)
        #pragma unroll
        for (int g = 0; g < G; ++g)
            xv[g][t] = __builtin_nontemporal_load(&x[(size_t)t * n4 + base + g * 256]);

    float m[G][4];
    int   k[G][4];
    #pragma unroll
    for (int g = 0; g < G; ++g)
        #pragma unroll
        for (int j = 0; j < 4; ++j) { m[g][j] = 0.5f * thre; k[g][j] = 0; }

    // Phase 1: integrate T1 frames (identical float sequence to fused).
    #pragma unroll
    for (int t = 0; t < T1; ++t)
        #pragma unroll
        for (int g = 0; g < G; ++g)
            #pragma unroll
            for (int j = 0; j < 4; ++j) {
                m[g][j] += xv[g][t][j];
                if (m[g][j] - thre >= EPS_C) { m[g][j] -= thre; k[g][j]++; }
            }

    // Phase 2: 7 relaxation steps with reverse spikes.
    #pragma unroll
    for (int t = 0; t < T1 - 1; ++t)
        #pragma unroll
        for (int g = 0; g < G; ++g)
            #pragma unroll
            for (int j = 0; j < 4; ++j) {
                const bool spike = (m[g][j] - thre >= EPS_C);
                const bool rev   = (-m[g][j] > 0.0f);
                m[g][j] += (rev ? thre : 0.0f) - (spike ? thre : 0.0f);
                k[g][j] += (spike ? 1 : 0) - (rev ? 1 : 0);
            }

    // Plain store: 4 MiB total, write-allocates into L2/IF$ for K2.
    #pragma unroll
    for (int g = 0; g < G; ++g) {
        cvec4 c;
        #pragma unroll
        for (int j = 0; j < 4; ++j) c[j] = (char)k[g][j];
        cnt[base + g * 256] = c;
    }
}

// ---------------- K2: write-phase (cached count load, NT out stores) ----
__global__ __launch_bounds__(256) void if_emit(
    const cvec4* __restrict__ cnt,
    const float* __restrict__ thresh,
    fvec4* __restrict__ out,
    int n4)
{
    const int base = blockIdx.x * (256 * G) + threadIdx.x;
    const float thre = thresh[0] / L_DIV;

    #pragma unroll
    for (int g = 0; g < G; ++g) {
        const cvec4 c = cnt[base + g * 256];   // IF$-resident from K1
        #pragma unroll
        for (int t = 0; t < T2; ++t) {
            fvec4 o;
            #pragma unroll
            for (int j = 0; j < 4; ++j)
                o[j] = ((int)c[j] > t) ? thre : 0.0f;
            __builtin_nontemporal_store(o, &out[(size_t)t * n4 + base + g * 256]);
        }
    }
}

// ---------------- Fallback: R13 fused kernel (ws too small) -------------
__global__ __launch_bounds__(256) void if_fwd_fused(
    const fvec4* __restrict__ x,
    const float* __restrict__ thresh,
    fvec4* __restrict__ out,
    int n4)
{
    const int base = blockIdx.x * (256 * G) + threadIdx.x;
    const float thre = thresh[0] / L_DIV;

    fvec4 xv[G][T1];
    #pragma unroll
    for (int t = 0; t < T1; ++t)
        #pragma unroll
        for (int g = 0; g < G; ++g)
            xv[g][t] = __builtin_nontemporal_load(&x[(size_t)t * n4 + base + g * 256]);

    float m[G][4], sc[G][4];
    #pragma unroll
    for (int g = 0; g < G; ++g)
        #pragma unroll
        for (int j = 0; j < 4; ++j) { m[g][j] = 0.5f * thre; sc[g][j] = 0.0f; }

    #pragma unroll
    for (int t = 0; t < T1; ++t)
        #pragma unroll
        for (int g = 0; g < G; ++g)
            #pragma unroll
            for (int j = 0; j < 4; ++j) {
                m[g][j] += xv[g][t][j];
                const float spike = (m[g][j] - thre >= EPS_C) ? thre : 0.0f;
                m[g][j] -= spike;
                sc[g][j] += spike;
            }

    #pragma unroll
    for (int t = 0; t < T1 - 1; ++t)
        #pragma unroll
        for (int g = 0; g < G; ++g)
            #pragma unroll
            for (int j = 0; j < 4; ++j) {
                const float spike = (m[g][j] - thre >= EPS_C) ? thre : 0.0f;
                const float rev   = (-m[g][j] > 0.0f) ? thre : 0.0f;
                m[g][j] = m[g][j] - spike + rev;
                sc[g][j] += spike - rev;
            }

    #pragma unroll
    for (int t = 0; t < T2; ++t) {
        const float cut = (float)(t + 1) * thre;
        #pragma unroll
        for (int g = 0; g < G; ++g) {
            fvec4 o;
            #pragma unroll
            for (int j = 0; j < 4; ++j)
                o[j] = (sc[g][j] - cut >= EPS_C) ? thre : 0.0f;
            out[(size_t)t * n4 + base + g * 256] = o;
        }
    }
}

extern "C" void kernel_launch(void* const* d_in, const int* in_sizes, int n_in,
                              void* d_out, int out_size, void* d_ws, size_t ws_size,
                              hipStream_t stream) {
    const fvec4* x      = (const fvec4*)d_in[0];
    const float* thresh = (const float*)d_in[1];
    fvec4*       out    = (fvec4*)d_out;

    const int N  = in_sizes[0] / T1;  // 4,194,304
    const int n4 = N / 4;             // 1,048,576

    const int block = 256;
    const int grid  = n4 / (block * G);  // 2048

    if (d_ws != nullptr && ws_size >= (size_t)n4 * 4) {
        cvec4* cnt = (cvec4*)d_ws;   // 4 MiB of int8 spike counts
        if_count<<<grid, block, 0, stream>>>(x, thresh, cnt, n4);
        if_emit<<<grid, block, 0, stream>>>(cnt, thresh, out, n4);
    } else {
        if_fwd_fused<<<grid, block, 0, stream>>>(x, thresh, out, n4);
    }
}

// Round 13
// 224.499 us; speedup vs baseline: 1.0181x; 1.0181x over previous
//
#include <hip/hip_runtime.h>

// Integrate-and-fire SNN forward (IF_88957362634870) -- FINAL CONFIG.
// x: 8 frames of N = 4,194,304 fp32 (134 MB); out: 8 frames (134 MB).
//
// Measured machine envelope (R11-R14, clean per-kernel counters):
//   pure write (fill/NT stores):      6.6 TB/s
//   pure NT read (R14 K1):           ~2.5 TB/s  <- machine read cap
//   mixed fused NT/NT (R11):          3.8 TB/s combined, kernel ~70 us
//   direction-pure split (R14):       ~75 us (54 read + 20 write + gap)
//   cached reads (R12):               ~84 us (mixed IF$/HBM path slower)
//   ROCm runtime's own D2D restore:   2.8 TB/s
// Fused NT/NT wins: write stream partially hides under the read-capped
// 54 us floor. dur_us = kernel (~70) + ~153 us fixed harness reset
// (512 MiB poison fill @ 80 us + restore copy), not controllable here.
// Read-bound floor 54 us => ideal dur ~207; residual ~16 us is
// write-on-read contention the split test proved irreducible.
//
// Phase 3 closed form (R7/R8-verified, exact at thre=2^-3):
//   out[t][i] = thre * [ sc[i] - (t+1)*thre >= EPS ]  (fires are a prefix).

#define T1 8
#define T2 8
#define L_DIV 8.0f
#define EPS_C (-8e-05f)
#define G 2            // float4-groups per thread

typedef float fvec4 __attribute__((ext_vector_type(4)));

__global__ __launch_bounds__(256) void if_fwd_fused(
    const fvec4* __restrict__ x,
    const float* __restrict__ thresh,
    fvec4* __restrict__ out,
    int n4)
{
    const int base = blockIdx.x * (256 * G) + threadIdx.x;
    const float thre = thresh[0] / L_DIV;

    // NT loads: stream x around L2/IF$ (beats cached path, R11 vs R12).
    fvec4 xv[G][T1];
    #pragma unroll
    for (int t = 0; t < T1; ++t)
        #pragma unroll
        for (int g = 0; g < G; ++g)
            xv[g][t] = __builtin_nontemporal_load(&x[(size_t)t * n4 + base + g * 256]);

    float m[G][4], sc[G][4];
    #pragma unroll
    for (int g = 0; g < G; ++g)
        #pragma unroll
        for (int k = 0; k < 4; ++k) { m[g][k] = 0.5f * thre; sc[g][k] = 0.0f; }

    // Phase 1: integrate T1 frames, fire-and-subtract.
    #pragma unroll
    for (int t = 0; t < T1; ++t)
        #pragma unroll
        for (int g = 0; g < G; ++g)
            #pragma unroll
            for (int k = 0; k < 4; ++k) {
                m[g][k] += xv[g][t][k];
                const float spike = (m[g][k] - thre >= EPS_C) ? thre : 0.0f;
                m[g][k] -= spike;
                sc[g][k] += spike;
            }

    // Phase 2: 7 relaxation steps with reverse spikes (register-only).
    #pragma unroll
    for (int t = 0; t < T1 - 1; ++t)
        #pragma unroll
        for (int g = 0; g < G; ++g)
            #pragma unroll
            for (int k = 0; k < 4; ++k) {
                const float spike = (m[g][k] - thre >= EPS_C) ? thre : 0.0f;
                const float rev   = (-m[g][k] > 0.0f) ? thre : 0.0f;
                m[g][k] = m[g][k] - spike + rev;
                sc[g][k] += spike - rev;
            }

    // Phase 3: closed-form emission, NT stores (R11 config: best measured).
    #pragma unroll
    for (int t = 0; t < T2; ++t) {
        const float cut = (float)(t + 1) * thre;
        #pragma unroll
        for (int g = 0; g < G; ++g) {
            fvec4 o;
            #pragma unroll
            for (int k = 0; k < 4; ++k)
                o[k] = (sc[g][k] - cut >= EPS_C) ? thre : 0.0f;
            __builtin_nontemporal_store(o, &out[(size_t)t * n4 + base + g * 256]);
        }
    }
}

extern "C" void kernel_launch(void* const* d_in, const int* in_sizes, int n_in,
                              void* d_out, int out_size, void* d_ws, size_t ws_size,
                              hipStream_t stream) {
    const fvec4* x      = (const fvec4*)d_in[0];
    const float* thresh = (const float*)d_in[1];
    fvec4*       out    = (fvec4*)d_out;

    const int N  = in_sizes[0] / T1;  // 4,194,304
    const int n4 = N / 4;             // 1,048,576

    const int block = 256;
    const int grid  = n4 / (block * G);  // 2048
    if_fwd_fused<<<grid, block, 0, stream>>>(x, thresh, out, n4);
}